// Round 11
// baseline (61.616 us; speedup 1.0000x reference)
//
#include <hip/hip_runtime.h>

#define IN_F     512
#define OUT_F    10240
#define NPROJ    6
#define THREADS  512
#define PER_T    (OUT_F / THREADS)   // 20 outputs per thread
#define ROWS     4                   // batch rows per pass
#define NPASS    2                   // passes per block (8 rows total)
#define NBINS    256
#define CAND_CAP 128
#define NWAVES   (THREADS / 64)
#define BIN_OFF  8064u               // (bits>>17) of 0.5f; bins cover [0.5, 8)

typedef float    float4v __attribute__((ext_vector_type(4)));
typedef unsigned uint4v  __attribute__((ext_vector_type(4)));

template<int N> struct IC { static constexpr int value = N; };

// One block = 8 batch rows as two straight-line passes of 4.
// Both tiles staged + all select state zeroed before the first barrier, so
// pass 0's fire-and-forget stores drain under pass 1's gather (no barrier
// between them; disjoint LDS). amdgpu_waves_per_eu(4,4) pins occupancy at
// 4 waves/EU so the allocator keeps the full 128-VGPR budget (anti-spill:
// rounds 5/6/8 all spilled when the heuristic chased 8 waves/EU).
// Per pass: round-10 static-bit-bin selection (exact, tie-correct).
__global__ __launch_bounds__(THREADS)
__attribute__((amdgpu_waves_per_eu(4, 4)))
void flyhash_wta_kernel(
    const float* __restrict__ inp,
    const int*   __restrict__ proj,
    const int*   __restrict__ hlen,
    float*       __restrict__ out,
    int batch)
{
    __shared__ float4v  s_rowT[NPASS][IN_F];            // 16 KB
    __shared__ unsigned s_hist[NPASS][ROWS][NBINS];     // 8 KB
    __shared__ unsigned s_bin[NPASS][ROWS];
    __shared__ float    s_cand[NPASS][ROWS][CAND_CAP];  // 4 KB
    __shared__ unsigned s_cnt[NPASS][ROWS];
    __shared__ float    s_kth[NPASS][ROWS];
    __shared__ int      s_pc[ROWS][NWAVES];             // bisection scratch

    const int t    = threadIdx.x;
    const int lane = t & 63;
    const int wave = t >> 6;
    const int b0   = blockIdx.x * (ROWS * NPASS);

    // --- stage BOTH tiles transposed (linear LDS writes); zero ALL state ---
    {
        const int r  = t & 3;
        const int cb = t >> 2;
#pragma unroll
        for (int g = 0; g < NPASS; ++g) {
            int br = b0 + g * ROWS + r;
            if (br >= batch) br = batch - 1;       // clamp (reads only)
            const float* gp = inp + (size_t)br * IN_F;
#pragma unroll
            for (int p = 0; p < 4; ++p) {
                const int c = cb + p * (THREADS / 4);
                ((float*)&s_rowT[g][0])[c * 4 + r] = gp[c];
            }
        }
    }
#pragma unroll
    for (int z = 0; z < (NPASS * ROWS * NBINS) / THREADS; ++z)   // 4 iters
        ((unsigned*)s_hist)[t + z * THREADS] = 0u;
    if (t < NPASS * ROWS) {
        ((unsigned*)s_cnt)[t] = 0u;
        ((float*)s_kth)[t]    = 0.0f;
    }
    __syncthreads();

    const int k0 = hlen[0];

    auto do_pass = [&](auto gc) {
        constexpr int G = decltype(gc)::value;

        // --- gather: one ds_read_b128 per index serves all 4 rows ---
        float4v acc[PER_T];
#pragma unroll
        for (int i = 0; i < PER_T; ++i) {
            const int o = t + i * THREADS;
            const int2* ip = (const int2*)(proj + (size_t)o * NPROJ);
            const int2 p0 = ip[0];
            const int2 p1 = ip[1];
            const int2 p2 = ip[2];
            // same per-component summation order as rounds 1-10 (absmax 0)
            const float4v a01 = s_rowT[G][p0.x] + s_rowT[G][p0.y];
            const float4v a23 = s_rowT[G][p1.x] + s_rowT[G][p1.y];
            const float4v a45 = s_rowT[G][p2.x] + s_rowT[G][p2.y];
            acc[i] = (a01 + a23) + a45;
        }

        // --- per-thread per-row max ---
        float4v tmax = acc[0];
#pragma unroll
        for (int i = 1; i < PER_T; ++i) {
            tmax.x = fmaxf(tmax.x, acc[i].x);
            tmax.y = fmaxf(tmax.y, acc[i].y);
            tmax.z = fmaxf(tmax.z, acc[i].z);
            tmax.w = fmaxf(tmax.w, acc[i].w);
        }

        // --- static-bit histogram of thread-maxes: 4 atomics/thread ---
#pragma unroll
        for (int r = 0; r < ROWS; ++r) {
            int key = (int)(__float_as_uint(tmax[r]) >> 17) - (int)BIN_OFF;
            key = key < 0 ? 0 : (key > NBINS - 1 ? NBINS - 1 : key);
            atomicAdd(&s_hist[G][r][key], 1u);
        }
        __syncthreads();

        // --- suffix scan on max-histogram: wave r -> row r ---
        if (wave < ROWS) {
            const uint4v h = ((const uint4v*)&s_hist[G][wave][0])[lane];
            const unsigned s3 = h.w;
            const unsigned s2 = h.z + s3;
            const unsigned s1 = h.y + s2;
            const unsigned s0 = h.x + s1;
            unsigned T = s0;
#pragma unroll
            for (int d = 1; d < 64; d <<= 1) {
                const unsigned o = __shfl_down(T, d);
                if (lane + d < 64) T += o;
            }
            const unsigned A = T - s0;             // sum over lanes > lane
            const unsigned S0 = A + s0, S1 = A + s1, S2 = A + s2, S3 = A + s3;
            if (h.x && (int)S0 >= k0 && (int)(S0 - h.x) < k0) s_bin[G][wave] = 4u * lane + 0u;
            if (h.y && (int)S1 >= k0 && (int)(S1 - h.y) < k0) s_bin[G][wave] = 4u * lane + 1u;
            if (h.z && (int)S2 >= k0 && (int)(S2 - h.z) < k0) s_bin[G][wave] = 4u * lane + 2u;
            if (h.w && (int)S3 >= k0 && (int)(S3 - h.w) < k0) s_bin[G][wave] = 4u * lane + 3u;
            if (lane == 0 && (int)(A + s0) < k0) s_bin[G][wave] = 0u;   // k > #maxes
        }
        __syncthreads();

        // --- T4[r] = exact lower edge of selected bin (<= kth value) ---
        float4v T4;
#pragma unroll
        for (int r = 0; r < ROWS; ++r) {
            const unsigned B = s_bin[G][r];
            T4[r] = (B == 0u) ? 0.0f : __uint_as_float((B + BIN_OFF) << 17);
        }

        // --- collect candidates >= T (sparse atomics; original values) ---
#pragma unroll
        for (int i = 0; i < PER_T; ++i) {
#pragma unroll
            for (int r = 0; r < ROWS; ++r) {
                const float v = acc[i][r];
                if (v >= T4[r]) {
                    const unsigned idx = atomicAdd(&s_cnt[G][r], 1u);
                    if (idx < CAND_CAP) s_cand[G][r][idx] = v;
                }
            }
        }
        __syncthreads();

        // --- overflow fallback: exact uint bisection on count(>=x) ---
        unsigned ovf = 0;
#pragma unroll
        for (int r = 0; r < ROWS; ++r)
            if (s_cnt[G][r] > CAND_CAP) ovf |= (1u << r);

        if (ovf) {
            unsigned lo[ROWS], hi[ROWS];
#pragma unroll
            for (int r = 0; r < ROWS; ++r) {
                lo[r] = __float_as_uint(T4[r]);    // count(>=lo) >= k
                hi[r] = 0x41000000u;               // 8.0f: count(>=hi)==0
            }
            for (int it = 0; it < 34; ++it) {
                unsigned work = 0;
#pragma unroll
                for (int r = 0; r < ROWS; ++r)
                    if (((ovf >> r) & 1u) && hi[r] - lo[r] > 1u) work |= (1u << r);
                if (!work) break;
                unsigned mid[ROWS];
#pragma unroll
                for (int r = 0; r < ROWS; ++r) mid[r] = lo[r] + (hi[r] - lo[r]) / 2u;
                int c0 = 0, c1 = 0, c2 = 0, c3 = 0;
#pragma unroll
                for (int i = 0; i < PER_T; ++i) {
                    c0 += (__float_as_uint(acc[i].x) >= mid[0]);
                    c1 += (__float_as_uint(acc[i].y) >= mid[1]);
                    c2 += (__float_as_uint(acc[i].z) >= mid[2]);
                    c3 += (__float_as_uint(acc[i].w) >= mid[3]);
                }
#pragma unroll
                for (int d = 1; d < 64; d <<= 1) {
                    c0 += __shfl_xor(c0, d);
                    c1 += __shfl_xor(c1, d);
                    c2 += __shfl_xor(c2, d);
                    c3 += __shfl_xor(c3, d);
                }
                if (lane == 0) {
                    s_pc[0][wave] = c0; s_pc[1][wave] = c1;
                    s_pc[2][wave] = c2; s_pc[3][wave] = c3;
                }
                __syncthreads();
#pragma unroll
                for (int r = 0; r < ROWS; ++r) {
                    if ((work >> r) & 1u) {
                        int c = 0;
#pragma unroll
                        for (int w = 0; w < NWAVES; ++w) c += s_pc[r][w];
                        if (c >= k0) lo[r] = mid[r]; else hi[r] = mid[r];
                    }
                }
                __syncthreads();
            }
            if (t == 0) {
#pragma unroll
                for (int r = 0; r < ROWS; ++r)
                    if ((ovf >> r) & 1u) s_kth[G][r] = __uint_as_float(lo[r]);
            }
        }

        // --- exact rank select over candidates: wave r -> row r ---
        if (wave < ROWS && !((ovf >> wave) & 1u)) {
            const unsigned c = s_cnt[G][wave];
            for (unsigned s = lane; s < c; s += 64) {
                const float v = s_cand[G][wave][s];
                int gt = 0, eq = 0;
                for (unsigned j = 0; j < c; ++j) {
                    const float u = s_cand[G][wave][j];
                    gt += (u > v);
                    eq += (u == v);
                }
                if (gt < k0 && gt + eq >= k0) s_kth[G][wave] = v;  // ties: same value
            }
        }
        __syncthreads();
        const float4v kth4 = { s_kth[G][0], s_kth[G][1], s_kth[G][2], s_kth[G][3] };

        // --- fire-and-forget predicated coalesced stores; next pass's gather
        //     follows with NO barrier (disjoint LDS, staged up front) ---
#pragma unroll
        for (int r = 0; r < ROWS; ++r) {
            const int br = b0 + G * ROWS + r;
            if (br < batch) {
                float* orow = out + (size_t)br * OUT_F;
#pragma unroll
                for (int i = 0; i < PER_T; ++i) {
                    const float v = acc[i][r];
                    orow[t + i * THREADS] = (v >= kth4[r]) ? v : 0.0f;
                }
            }
        }
    };

    do_pass(IC<0>{});
    do_pass(IC<1>{});
}

extern "C" void kernel_launch(void* const* d_in, const int* in_sizes, int n_in,
                              void* d_out, int out_size, void* d_ws, size_t ws_size,
                              hipStream_t stream) {
    const float* inp  = (const float*)d_in[0];
    const int*   proj = (const int*)d_in[1];
    const int*   hlen = (const int*)d_in[2];
    float*       out  = (float*)d_out;

    const int batch  = in_sizes[0] / IN_F;                         // 4096
    const int blocks = (batch + ROWS * NPASS - 1) / (ROWS * NPASS); // 512

    hipLaunchKernelGGL(flyhash_wta_kernel, dim3(blocks), dim3(THREADS), 0, stream,
                       inp, proj, hlen, out, batch);
}